// Round 3
// baseline (205.931 us; speedup 1.0000x reference)
//
#include <hip/hip_runtime.h>

#define Bn 64
#define Ln 200
#define Dn 256
#define Kn 8
#define LPn 224          // L padded to multiple of 32 for 2-mtile GEMM blocks
#define EPSf 1e-5f
#define SCALEf 0.0625f   // 1/sqrt(256)

typedef short bf16x8 __attribute__((ext_vector_type(8)));
typedef float f32x4  __attribute__((ext_vector_type(4)));

__device__ __forceinline__ unsigned short f2bf(float f) {
    unsigned int u = __builtin_bit_cast(unsigned int, f);
    u += 0x7fffu + ((u >> 16) & 1u);     // RTNE
    return (unsigned short)(u >> 16);
}

__device__ __forceinline__ float wsum(float v) {
    v += __shfl_xor(v, 32, 64);
    v += __shfl_xor(v, 16, 64);
    v += __shfl_xor(v, 8, 64);
    v += __shfl_xor(v, 4, 64);
    v += __shfl_xor(v, 2, 64);
    v += __shfl_xor(v, 1, 64);
    return v;
}

// reduce within 16-lane groups (4 independent rows per wave share instructions)
__device__ __forceinline__ float gsum16(float v) {
    v += __shfl_xor(v, 1, 64);
    v += __shfl_xor(v, 2, 64);
    v += __shfl_xor(v, 4, 64);
    v += __shfl_xor(v, 8, 64);
    return v;
}

// ---------------- prep: LN(intentions), q rows, W_w -> MFMA-B fragment layout ----------------
__global__ __launch_bounds__(256) void kprep(
    const float* __restrict__ intentions, const float* __restrict__ g2, const float* __restrict__ b2,
    const float* __restrict__ loc, const float* __restrict__ glob,
    const float* __restrict__ pos, const float* __restrict__ rou,
    const float* __restrict__ g3, const float* __restrict__ b3,
    const int*   __restrict__ seq_len, const float* __restrict__ Ww,
    float* __restrict__ i2hat, float* __restrict__ q, unsigned short* __restrict__ wfrag)
{
    int blk = blockIdx.x, tid = threadIdx.x;
    int lane = tid & 63;
    if (blk < 2) {
        int k = blk * 4 + (tid >> 6);
        const float4 x4 = *(const float4*)(intentions + k * Dn + lane * 4);
        float x[4] = {x4.x, x4.y, x4.z, x4.w};
        float s1 = x[0] + x[1] + x[2] + x[3];
        float s2 = x[0]*x[0] + x[1]*x[1] + x[2]*x[2] + x[3]*x[3];
        s1 = wsum(s1); s2 = wsum(s2);
        float mu = s1 * (1.0f / Dn);
        float var = s2 * (1.0f / Dn) - mu * mu;
        float rs = rsqrtf(var + EPSf);
        const float4 gg = *(const float4*)(g2 + lane * 4);
        const float4 bb = *(const float4*)(b2 + lane * 4);
        float4 o;
        o.x = (x[0]-mu)*rs*gg.x + bb.x; o.y = (x[1]-mu)*rs*gg.y + bb.y;
        o.z = (x[2]-mu)*rs*gg.z + bb.z; o.w = (x[3]-mu)*rs*gg.w + bb.w;
        *(float4*)(i2hat + k * Dn + lane * 4) = o;
    } else if (blk < 34) {
        int wid = (blk - 2) * 4 + (tid >> 6);        // 0..127
        int s = wid / Bn, b = wid % Bn;
        const float* item = s ? glob : loc;
        int idx = seq_len[b] - 1;
        const float4 x4 = *(const float4*)(item + (b * Ln + idx) * Dn + lane * 4);
        const float4 p4 = *(const float4*)(pos + idx * Dn + lane * 4);
        const float4 r4 = *(const float4*)(rou + lane * 4);
        float x[4] = {x4.x + p4.x + r4.x, x4.y + p4.y + r4.y,
                      x4.z + p4.z + r4.z, x4.w + p4.w + r4.w};
        float s1 = x[0] + x[1] + x[2] + x[3];
        float s2 = x[0]*x[0] + x[1]*x[1] + x[2]*x[2] + x[3]*x[3];
        s1 = wsum(s1); s2 = wsum(s2);
        float mu = s1 * (1.0f / Dn);
        float var = s2 * (1.0f / Dn) - mu * mu;
        float rs = rsqrtf(var + EPSf);
        const float4 gg = *(const float4*)(g3 + lane * 4);
        const float4 bb = *(const float4*)(b3 + lane * 4);
        float4 o;
        o.x = (x[0]-mu)*rs*gg.x + bb.x; o.y = (x[1]-mu)*rs*gg.y + bb.y;
        o.z = (x[2]-mu)*rs*gg.z + bb.z; o.w = (x[3]-mu)*rs*gg.w + bb.w;
        *(float4*)(q + wid * Dn + lane * 4) = o;
    } else {
        // pack W_w into B-operand fragment order for mfma_f32_16x16x32_bf16
        int gt = (blk - 34) * 256 + tid;             // 0..8191
        int frag = gt >> 6, fl = gt & 63;            // frag = kt*16+nt
        int kt = frag >> 4, nt = frag & 15;
        int d = nt * 16 + (fl & 15);
        int e = kt * 32 + (fl >> 4) * 8;
        const float* src = Ww + d * Dn + e;
        unsigned short tmp[8];
#pragma unroll
        for (int j = 0; j < 8; ++j) tmp[j] = f2bf(src[j]);
        ushort4 lo, hi;
        lo.x = tmp[0]; lo.y = tmp[1]; lo.z = tmp[2]; lo.w = tmp[3];
        hi.x = tmp[4]; hi.y = tmp[5]; hi.z = tmp[6]; hi.w = tmp[7];
        unsigned short* dst = wfrag + (size_t)gt * 8;
        *(ushort4*)(dst) = lo;
        *(ushort4*)(dst + 4) = hi;
    }
}

// ---------------- per-row: stats, score softmax, key_hat(bf16), q.kh ----------------
// 16 lanes per row, 4 rows per wave, 16 rows per block. Reductions batched across rows.
__global__ __launch_bounds__(256) void krow(
    const float* __restrict__ loc, const float* __restrict__ glob, const float* __restrict__ pos,
    const float* __restrict__ g1, const float* __restrict__ b1,
    const float* __restrict__ g4, const float* __restrict__ b4,
    const float* __restrict__ i2hat, const float* __restrict__ q,
    float* __restrict__ score, float* __restrict__ stats, float* __restrict__ qkh,
    unsigned short* __restrict__ kh16)
{
    int gw = blockIdx.x * 4 + (threadIdx.x >> 6);   // global wave id
    int lane = threadIdx.x & 63;
    int grp = lane >> 4, l16 = lane & 15;
    int R = gw * 4 + grp;                            // global row id
    int s = R / (Bn * LPn);
    int rem = R % (Bn * LPn);
    int b = rem / LPn, l = rem % LPn;
    bool valid = l < Ln;
    int lc = valid ? l : 0;
    int doff = l16 * 16;

    const float* item = s ? glob : loc;
    const float* xrow = item + (size_t)(b * Ln + lc) * Dn + doff;
    const float* prow = pos + (size_t)lc * Dn + doff;

    float x[16], p[16];
#pragma unroll
    for (int v = 0; v < 4; ++v) {
        float4 xv = *(const float4*)(xrow + v * 4);
        float4 pv = *(const float4*)(prow + v * 4);
        x[v*4+0] = xv.x; x[v*4+1] = xv.y; x[v*4+2] = xv.z; x[v*4+3] = xv.w;
        p[v*4+0] = pv.x; p[v*4+1] = pv.y; p[v*4+2] = pv.z; p[v*4+3] = pv.w;
    }

    // item stats
    float s1 = 0.f, s2 = 0.f;
#pragma unroll
    for (int i = 0; i < 16; ++i) { s1 += x[i]; s2 = fmaf(x[i], x[i], s2); }
    s1 = gsum16(s1); s2 = gsum16(s2);
    float mu = s1 * (1.0f / Dn);
    float var = s2 * (1.0f / Dn) - mu * mu;
    float rs = rsqrtf(var + EPSf);

    // x1 = LN1(item)
    float x1[16];
#pragma unroll
    for (int v = 0; v < 4; ++v) {
        float4 gg = *(const float4*)(g1 + doff + v * 4);
        float4 bb = *(const float4*)(b1 + doff + v * 4);
        x1[v*4+0] = (x[v*4+0]-mu)*rs*gg.x + bb.x;
        x1[v*4+1] = (x[v*4+1]-mu)*rs*gg.y + bb.y;
        x1[v*4+2] = (x[v*4+2]-mu)*rs*gg.z + bb.z;
        x1[v*4+3] = (x[v*4+3]-mu)*rs*gg.w + bb.w;
    }

    // 8 intention logits (batched reductions)
    float lg[Kn];
#pragma unroll
    for (int k = 0; k < Kn; ++k) {
        const float* iv = i2hat + k * Dn + doff;
        float pk = 0.f;
#pragma unroll
        for (int v = 0; v < 4; ++v) {
            float4 i4 = *(const float4*)(iv + v * 4);
            pk = fmaf(x1[v*4+0], i4.x, pk); pk = fmaf(x1[v*4+1], i4.y, pk);
            pk = fmaf(x1[v*4+2], i4.z, pk); pk = fmaf(x1[v*4+3], i4.w, pk);
        }
        lg[k] = gsum16(pk);
    }
    float mx = -1e30f;
#pragma unroll
    for (int k = 0; k < Kn; ++k) { lg[k] *= SCALEf; mx = fmaxf(mx, lg[k]); }
    float se = 0.f;
    float ex[Kn];
#pragma unroll
    for (int k = 0; k < Kn; ++k) { ex[k] = __expf(lg[k] - mx); se += ex[k]; }
    float inv = 1.0f / se;
    size_t r = (size_t)(s * Bn + b) * Ln + l;
    if (valid) {
        if (l16 < Kn) score[r * Kn + l16] = ex[l16] * inv;
        if (l16 == 0) { float2 st; st.x = mu; st.y = var; *(float2*)(stats + 2 * r) = st; }
    }

    // key_hat = LN4(item + pos)
    float t1 = 0.f, t2 = 0.f;
    float y[16];
#pragma unroll
    for (int i = 0; i < 16; ++i) { y[i] = x[i] + p[i]; t1 += y[i]; t2 = fmaf(y[i], y[i], t2); }
    t1 = gsum16(t1); t2 = gsum16(t2);
    float muy = t1 * (1.0f / Dn);
    float vay = t2 * (1.0f / Dn) - muy * muy;
    float rsy = rsqrtf(vay + EPSf);
    float kh[16];
#pragma unroll
    for (int v = 0; v < 4; ++v) {
        float4 gg = *(const float4*)(g4 + doff + v * 4);
        float4 bb = *(const float4*)(b4 + doff + v * 4);
        kh[v*4+0] = (y[v*4+0]-muy)*rsy*gg.x + bb.x;
        kh[v*4+1] = (y[v*4+1]-muy)*rsy*gg.y + bb.y;
        kh[v*4+2] = (y[v*4+2]-muy)*rsy*gg.z + bb.z;
        kh[v*4+3] = (y[v*4+3]-muy)*rsy*gg.w + bb.w;
    }
    ushort4 kv[4];
#pragma unroll
    for (int v = 0; v < 4; ++v) {
        kv[v].x = valid ? f2bf(kh[v*4+0]) : (unsigned short)0;
        kv[v].y = valid ? f2bf(kh[v*4+1]) : (unsigned short)0;
        kv[v].z = valid ? f2bf(kh[v*4+2]) : (unsigned short)0;
        kv[v].w = valid ? f2bf(kh[v*4+3]) : (unsigned short)0;
    }
    unsigned short* khrow = kh16 + ((size_t)(s * Bn + b) * LPn + l) * Dn + doff;
    *(ushort4*)(khrow)      = kv[0];
    *(ushort4*)(khrow + 4)  = kv[1];
    *(ushort4*)(khrow + 8)  = kv[2];
    *(ushort4*)(khrow + 12) = kv[3];

    // q . key_hat
    const float* qrow = q + (size_t)(s * Bn + b) * Dn + doff;
    float pq = 0.f;
#pragma unroll
    for (int v = 0; v < 4; ++v) {
        float4 q4 = *(const float4*)(qrow + v * 4);
        pq = fmaf(kh[v*4+0], q4.x, pq); pq = fmaf(kh[v*4+1], q4.y, pq);
        pq = fmaf(kh[v*4+2], q4.z, pq); pq = fmaf(kh[v*4+3], q4.w, pq);
    }
    pq = gsum16(pq);
    if (valid && l16 == 0) qkh[r] = pq;
}

// ---------------- GEMM: T = kh @ Ww^T, fused relu + q-dot epilogue -> w logits ----------------
// grid = 128 sb * 7 mtile-groups (2 mtiles each); block = 4 waves; wave wv = d-cols [wv*64,+64)
__global__ __launch_bounds__(256) void kgemm(
    const unsigned short* __restrict__ kh16, const unsigned short* __restrict__ wfrag,
    const float* __restrict__ q, const float* __restrict__ Wb,
    const float* __restrict__ qkh, float* __restrict__ wlogit)
{
    int blk = blockIdx.x;
    int sb = blk / 7, mtg = blk % 7;
    int wv = threadIdx.x >> 6, lane = threadIdx.x & 63;

    f32x4 acc[2][4];
#pragma unroll
    for (int mt = 0; mt < 2; ++mt)
#pragma unroll
        for (int nt = 0; nt < 4; ++nt) { acc[mt][nt][0]=0.f; acc[mt][nt][1]=0.f; acc[mt][nt][2]=0.f; acc[mt][nt][3]=0.f; }

    int arow = lane & 15;
    int acol = (lane >> 4) * 8;
    const unsigned short* arowp = kh16 + ((size_t)sb * LPn + mtg * 32 + arow) * Dn + acol;
    const unsigned short* bbase = wfrag + (size_t)(wv * 4) * 64 * 8 + (size_t)lane * 8;

#pragma unroll
    for (int kt = 0; kt < 8; ++kt) {
        bf16x8 af0 = *(const bf16x8*)(arowp + kt * 32);
        bf16x8 af1 = *(const bf16x8*)(arowp + 16 * Dn + kt * 32);
#pragma unroll
        for (int nt = 0; nt < 4; ++nt) {
            bf16x8 bf = *(const bf16x8*)(bbase + ((size_t)(kt * 16 + nt) * 64) * 8);
            acc[0][nt] = __builtin_amdgcn_mfma_f32_16x16x32_bf16(af0, bf, acc[0][nt], 0, 0, 0);
            acc[1][nt] = __builtin_amdgcn_mfma_f32_16x16x32_bf16(af1, bf, acc[1][nt], 0, 0, 0);
        }
    }

    // epilogue: partial[row] = sum_d q[d]*relu(T[row][d] + Wb[d]) over this wave's 64 d-cols
    int col = lane & 15, quad = lane >> 4;
    float qv[4], wbv[4];
#pragma unroll
    for (int nt = 0; nt < 4; ++nt) {
        int d = (wv * 4 + nt) * 16 + col;
        qv[nt] = q[(size_t)sb * Dn + d];
        wbv[nt] = Wb[d];
    }
    __shared__ float part[4][32];
#pragma unroll
    for (int mt = 0; mt < 2; ++mt) {
#pragma unroll
        for (int j = 0; j < 4; ++j) {
            float t = 0.f;
#pragma unroll
            for (int nt = 0; nt < 4; ++nt) {
                float v = acc[mt][nt][j] + wbv[nt];
                v = fmaxf(v, 0.f);
                t = fmaf(qv[nt], v, t);
            }
            t += __shfl_xor(t, 1, 64);
            t += __shfl_xor(t, 2, 64);
            t += __shfl_xor(t, 4, 64);
            t += __shfl_xor(t, 8, 64);
            if (col == 0) part[wv][mt * 16 + quad * 4 + j] = t;
        }
    }
    __syncthreads();
    int t = threadIdx.x;
    if (t < 32) {
        int l = mtg * 32 + t;
        if (l < Ln)
            wlogit[(size_t)sb * Ln + l] = qkh[(size_t)sb * Ln + l]
                + part[0][t] + part[1][t] + part[2][t] + part[3][t];
    }
}

// ---------------- softmax over L per (s,b) ----------------
__global__ __launch_bounds__(256) void ksoft(const float* __restrict__ wlogit, float* __restrict__ wsoft)
{
    int sb = blockIdx.x, t = threadIdx.x;
    __shared__ float red[4];
    float lg = (t < Ln) ? wlogit[(size_t)sb * Ln + t] * SCALEf : -1e30f;
    float m = lg;
#pragma unroll
    for (int mk = 32; mk >= 1; mk >>= 1) m = fmaxf(m, __shfl_xor(m, mk, 64));
    if ((t & 63) == 0) red[t >> 6] = m;
    __syncthreads();
    m = fmaxf(fmaxf(red[0], red[1]), fmaxf(red[2], red[3]));
    __syncthreads();
    float ex = (t < Ln) ? __expf(lg - m) : 0.f;
    float sm = ex;
#pragma unroll
    for (int mk = 32; mk >= 1; mk >>= 1) sm += __shfl_xor(sm, mk, 64);
    if ((t & 63) == 0) red[t >> 6] = sm;
    __syncthreads();
    sm = red[0] + red[1] + red[2] + red[3];
    if (t < Ln) wsoft[(size_t)sb * Ln + t] = ex / sm;
}

// ---------------- output: sum of LN5(score*w*item) over both sources ----------------
// 4 (b,l) rows per block, 64 lanes per row, float4 per lane
__global__ __launch_bounds__(256) void kout(
    const float* __restrict__ loc, const float* __restrict__ glob,
    const float* __restrict__ score, const float* __restrict__ stats, const float* __restrict__ wsoft,
    const float* __restrict__ g5, const float* __restrict__ b5, float* __restrict__ out)
{
    int rr = threadIdx.x >> 6;
    int lane = threadIdx.x & 63;
    int row = blockIdx.x * 4 + rr;                   // (b,l) flat
    int b = row / Ln, l = row % Ln;
    size_t r0 = (size_t)b * Ln + l;
    size_t r1 = (size_t)(Bn + b) * Ln + l;

    float4 x0 = *(const float4*)(loc + (size_t)row * Dn + lane * 4);
    float4 x1 = *(const float4*)(glob + (size_t)row * Dn + lane * 4);
    float2 st0 = *(const float2*)(stats + 2 * r0);
    float2 st1 = *(const float2*)(stats + 2 * r1);
    float w0 = wsoft[r0], w1 = wsoft[r1];
    float4 g5v = *(const float4*)(g5 + lane * 4);
    float4 b5v = *(const float4*)(b5 + lane * 4);

    float4 dx0, dx1;
    dx0.x = x0.x - st0.x; dx0.y = x0.y - st0.x; dx0.z = x0.z - st0.x; dx0.w = x0.w - st0.x;
    dx1.x = x1.x - st1.x; dx1.y = x1.y - st1.x; dx1.z = x1.z - st1.x; dx1.w = x1.w - st1.x;

    float* obase = out + ((size_t)b * Kn * Ln + l) * Dn + lane * 4;
#pragma unroll
    for (int k = 0; k < Kn; ++k) {
        float c0 = score[r0 * Kn + k] * w0;
        float c1 = score[r1 * Kn + k] * w1;
        float a0 = c0 * rsqrtf(fmaf(c0 * c0, st0.y, EPSf));
        float a1 = c1 * rsqrtf(fmaf(c1 * c1, st1.y, EPSf));
        float4 o;
        o.x = fmaf(g5v.x, fmaf(a0, dx0.x, a1 * dx1.x), 2.0f * b5v.x);
        o.y = fmaf(g5v.y, fmaf(a0, dx0.y, a1 * dx1.y), 2.0f * b5v.y);
        o.z = fmaf(g5v.z, fmaf(a0, dx0.z, a1 * dx1.z), 2.0f * b5v.z);
        o.w = fmaf(g5v.w, fmaf(a0, dx0.w, a1 * dx1.w), 2.0f * b5v.w);
        *(float4*)(obase + (size_t)k * Ln * Dn) = o;
    }
}

extern "C" void kernel_launch(void* const* d_in, const int* in_sizes, int n_in,
                              void* d_out, int out_size, void* d_ws, size_t ws_size,
                              hipStream_t stream) {
    const float* loc   = (const float*)d_in[0];
    const float* glob  = (const float*)d_in[1];
    const float* inten = (const float*)d_in[2];
    const float* pos   = (const float*)d_in[3];
    const float* rou   = (const float*)d_in[4];
    const float* Ww    = (const float*)d_in[5];
    const float* Wb    = (const float*)d_in[6];
    const float* g1 = (const float*)d_in[7],  *b1 = (const float*)d_in[8];
    const float* g2 = (const float*)d_in[9],  *b2 = (const float*)d_in[10];
    const float* g3 = (const float*)d_in[11], *b3 = (const float*)d_in[12];
    const float* g4 = (const float*)d_in[13], *b4 = (const float*)d_in[14];
    const float* g5 = (const float*)d_in[15], *b5 = (const float*)d_in[16];
    const int* seq_len = (const int*)d_in[17];
    float* out = (float*)d_out;

    char* ws = (char*)d_ws;
    size_t off = 0;
    float* i2hat = (float*)(ws + off);            off += (size_t)Kn * Dn * 4;
    float* q     = (float*)(ws + off);            off += (size_t)2 * Bn * Dn * 4;
    unsigned short* wfrag = (unsigned short*)(ws + off); off += (size_t)Dn * Dn * 2;
    unsigned short* kh16  = (unsigned short*)(ws + off); off += (size_t)2 * Bn * LPn * Dn * 2;
    float* score  = (float*)(ws + off);           off += (size_t)2 * Bn * Ln * Kn * 4;
    float* stats  = (float*)(ws + off);           off += (size_t)2 * Bn * Ln * 2 * 4;
    float* qkh    = (float*)(ws + off);           off += (size_t)2 * Bn * Ln * 4;
    float* wlogit = (float*)(ws + off);           off += (size_t)2 * Bn * Ln * 4;
    float* wsoft  = (float*)(ws + off);           off += (size_t)2 * Bn * Ln * 4;

    kprep<<<66, 256, 0, stream>>>(inten, g2, b2, loc, glob, pos, rou, g3, b3, seq_len, Ww,
                                  i2hat, q, wfrag);
    krow<<<(2 * Bn * LPn) / 16, 256, 0, stream>>>(loc, glob, pos, g1, b1, g4, b4, i2hat, q,
                                                  score, stats, qkh, kh16);
    kgemm<<<128 * 7, 256, 0, stream>>>(kh16, wfrag, q, Wb, qkh, wlogit);
    ksoft<<<2 * Bn, 256, 0, stream>>>(wlogit, wsoft);
    kout<<<Bn * Ln / 4, 256, 0, stream>>>(loc, glob, score, stats, wsoft, g5, b5, out);
}

// Round 4
// 200.406 us; speedup vs baseline: 1.0276x; 1.0276x over previous
//
#include <hip/hip_runtime.h>

#define Bn 64
#define Ln 200
#define Dn 256
#define Kn 8
#define LPn 224          // L padded to 7 groups of 32 rows
#define LDSW 264         // LDS row stride in bf16 elements (256 + 8 pad)
#define EPSf 1e-5f
#define SCALEf 0.0625f   // 1/sqrt(256)

typedef short bf16x8 __attribute__((ext_vector_type(8)));
typedef float f32x4  __attribute__((ext_vector_type(4)));

__device__ __forceinline__ unsigned short f2bf(float f) {
    unsigned int u = __builtin_bit_cast(unsigned int, f);
    u += 0x7fffu + ((u >> 16) & 1u);     // RTNE
    return (unsigned short)(u >> 16);
}

__device__ __forceinline__ float wsum(float v) {
    v += __shfl_xor(v, 32, 64);
    v += __shfl_xor(v, 16, 64);
    v += __shfl_xor(v, 8, 64);
    v += __shfl_xor(v, 4, 64);
    v += __shfl_xor(v, 2, 64);
    v += __shfl_xor(v, 1, 64);
    return v;
}

// reduce within 16-lane groups (4 independent rows per wave share instructions)
__device__ __forceinline__ float gsum16(float v) {
    v += __shfl_xor(v, 1, 64);
    v += __shfl_xor(v, 2, 64);
    v += __shfl_xor(v, 4, 64);
    v += __shfl_xor(v, 8, 64);
    return v;
}

// ---------------- prep: LN(intentions), q rows, W_w -> MFMA-B fragment layout ----------------
__global__ __launch_bounds__(256) void kprep(
    const float* __restrict__ intentions, const float* __restrict__ g2, const float* __restrict__ b2,
    const float* __restrict__ loc, const float* __restrict__ glob,
    const float* __restrict__ pos, const float* __restrict__ rou,
    const float* __restrict__ g3, const float* __restrict__ b3,
    const int*   __restrict__ seq_len, const float* __restrict__ Ww,
    float* __restrict__ i2hat, float* __restrict__ q, unsigned short* __restrict__ wfrag)
{
    int blk = blockIdx.x, tid = threadIdx.x;
    int lane = tid & 63;
    if (blk < 2) {
        int k = blk * 4 + (tid >> 6);
        const float4 x4 = *(const float4*)(intentions + k * Dn + lane * 4);
        float x[4] = {x4.x, x4.y, x4.z, x4.w};
        float s1 = x[0] + x[1] + x[2] + x[3];
        float s2 = x[0]*x[0] + x[1]*x[1] + x[2]*x[2] + x[3]*x[3];
        s1 = wsum(s1); s2 = wsum(s2);
        float mu = s1 * (1.0f / Dn);
        float var = s2 * (1.0f / Dn) - mu * mu;
        float rs = rsqrtf(var + EPSf);
        const float4 gg = *(const float4*)(g2 + lane * 4);
        const float4 bb = *(const float4*)(b2 + lane * 4);
        float4 o;
        o.x = (x[0]-mu)*rs*gg.x + bb.x; o.y = (x[1]-mu)*rs*gg.y + bb.y;
        o.z = (x[2]-mu)*rs*gg.z + bb.z; o.w = (x[3]-mu)*rs*gg.w + bb.w;
        *(float4*)(i2hat + k * Dn + lane * 4) = o;
    } else if (blk < 34) {
        int wid = (blk - 2) * 4 + (tid >> 6);        // 0..127
        int s = wid / Bn, b = wid % Bn;
        const float* item = s ? glob : loc;
        int idx = seq_len[b] - 1;
        const float4 x4 = *(const float4*)(item + (b * Ln + idx) * Dn + lane * 4);
        const float4 p4 = *(const float4*)(pos + idx * Dn + lane * 4);
        const float4 r4 = *(const float4*)(rou + lane * 4);
        float x[4] = {x4.x + p4.x + r4.x, x4.y + p4.y + r4.y,
                      x4.z + p4.z + r4.z, x4.w + p4.w + r4.w};
        float s1 = x[0] + x[1] + x[2] + x[3];
        float s2 = x[0]*x[0] + x[1]*x[1] + x[2]*x[2] + x[3]*x[3];
        s1 = wsum(s1); s2 = wsum(s2);
        float mu = s1 * (1.0f / Dn);
        float var = s2 * (1.0f / Dn) - mu * mu;
        float rs = rsqrtf(var + EPSf);
        const float4 gg = *(const float4*)(g3 + lane * 4);
        const float4 bb = *(const float4*)(b3 + lane * 4);
        float4 o;
        o.x = (x[0]-mu)*rs*gg.x + bb.x; o.y = (x[1]-mu)*rs*gg.y + bb.y;
        o.z = (x[2]-mu)*rs*gg.z + bb.z; o.w = (x[3]-mu)*rs*gg.w + bb.w;
        *(float4*)(q + wid * Dn + lane * 4) = o;
    } else {
        // pack W_w into B-operand fragment order for mfma_f32_16x16x32_bf16
        int gt = (blk - 34) * 256 + tid;             // 0..8191
        int frag = gt >> 6, fl = gt & 63;            // frag = kt*16+nt
        int kt = frag >> 4, nt = frag & 15;
        int d = nt * 16 + (fl & 15);
        int e = kt * 32 + (fl >> 4) * 8;
        const float* src = Ww + d * Dn + e;
        unsigned short tmp[8];
#pragma unroll
        for (int j = 0; j < 8; ++j) tmp[j] = f2bf(src[j]);
        ushort4 lo, hi;
        lo.x = tmp[0]; lo.y = tmp[1]; lo.z = tmp[2]; lo.w = tmp[3];
        hi.x = tmp[4]; hi.y = tmp[5]; hi.z = tmp[6]; hi.w = tmp[7];
        unsigned short* dst = wfrag + (size_t)gt * 8;
        *(ushort4*)(dst) = lo;
        *(ushort4*)(dst + 4) = hi;
    }
}

// ---------------- fused row-prep + GEMM ----------------
// block = (sb, 32-row group). Phase 1: LN stats/score/key_hat -> LDS (MFMA-A friendly).
// Phase 2: T = kh @ Ww^T from LDS, fused relu + q-dot epilogue -> w logits.
__global__ __launch_bounds__(256) void kfused(
    const float* __restrict__ loc, const float* __restrict__ glob, const float* __restrict__ pos,
    const float* __restrict__ g1, const float* __restrict__ b1,
    const float* __restrict__ g4, const float* __restrict__ b4,
    const float* __restrict__ i2hat, const float* __restrict__ q,
    const unsigned short* __restrict__ wfrag, const float* __restrict__ Wb,
    float* __restrict__ score, float* __restrict__ stats, float* __restrict__ wlogit)
{
    __shared__ unsigned short khL[32 * LDSW];
    __shared__ float part[4][32];
    __shared__ float qkhL[32];

    int sb = blockIdx.x / 7, mtg = blockIdx.x % 7;
    int s = sb / Bn, b = sb % Bn;
    int wv = threadIdx.x >> 6, lane = threadIdx.x & 63;
    int grp = lane >> 4, l16 = lane & 15;
    int doff = l16 * 16;
    const float* item = s ? glob : loc;

    // ---- phase 1: 8 rows per wave, 2 iterations of 4 rows ----
#pragma unroll
    for (int it = 0; it < 2; ++it) {
        int rowL = wv * 8 + it * 4 + grp;            // 0..31 local row
        int l = mtg * 32 + rowL;                     // global l, 0..223
        bool valid = l < Ln;
        int lc = valid ? l : 0;

        const float* xrow = item + (size_t)(b * Ln + lc) * Dn + doff;
        const float* prow = pos + (size_t)lc * Dn + doff;
        float x[16], p[16];
#pragma unroll
        for (int v = 0; v < 4; ++v) {
            float4 xv = *(const float4*)(xrow + v * 4);
            float4 pv = *(const float4*)(prow + v * 4);
            x[v*4+0] = xv.x; x[v*4+1] = xv.y; x[v*4+2] = xv.z; x[v*4+3] = xv.w;
            p[v*4+0] = pv.x; p[v*4+1] = pv.y; p[v*4+2] = pv.z; p[v*4+3] = pv.w;
        }

        // item stats
        float s1 = 0.f, s2 = 0.f;
#pragma unroll
        for (int i = 0; i < 16; ++i) { s1 += x[i]; s2 = fmaf(x[i], x[i], s2); }
        s1 = gsum16(s1); s2 = gsum16(s2);
        float mu = s1 * (1.0f / Dn);
        float var = s2 * (1.0f / Dn) - mu * mu;
        float rs = rsqrtf(var + EPSf);

        // x1 = LN1(item); 8 intention logits
        float x1[16];
#pragma unroll
        for (int v = 0; v < 4; ++v) {
            float4 gg = *(const float4*)(g1 + doff + v * 4);
            float4 bb = *(const float4*)(b1 + doff + v * 4);
            x1[v*4+0] = (x[v*4+0]-mu)*rs*gg.x + bb.x;
            x1[v*4+1] = (x[v*4+1]-mu)*rs*gg.y + bb.y;
            x1[v*4+2] = (x[v*4+2]-mu)*rs*gg.z + bb.z;
            x1[v*4+3] = (x[v*4+3]-mu)*rs*gg.w + bb.w;
        }
        float lg[Kn];
#pragma unroll
        for (int k = 0; k < Kn; ++k) {
            const float* iv = i2hat + k * Dn + doff;
            float pk = 0.f;
#pragma unroll
            for (int v = 0; v < 4; ++v) {
                float4 i4 = *(const float4*)(iv + v * 4);
                pk = fmaf(x1[v*4+0], i4.x, pk); pk = fmaf(x1[v*4+1], i4.y, pk);
                pk = fmaf(x1[v*4+2], i4.z, pk); pk = fmaf(x1[v*4+3], i4.w, pk);
            }
            lg[k] = gsum16(pk);
        }
        float mx = -1e30f;
#pragma unroll
        for (int k = 0; k < Kn; ++k) { lg[k] *= SCALEf; mx = fmaxf(mx, lg[k]); }
        float se = 0.f;
        float ex[Kn];
#pragma unroll
        for (int k = 0; k < Kn; ++k) { ex[k] = __expf(lg[k] - mx); se += ex[k]; }
        float inv = 1.0f / se;
        size_t r = (size_t)sb * Ln + l;
        if (valid) {
            if (l16 < Kn) score[r * Kn + l16] = ex[l16] * inv;
            if (l16 == 0) { float2 st; st.x = mu; st.y = var; *(float2*)(stats + 2 * r) = st; }
        }

        // key_hat = LN4(item + pos) -> LDS (bf16)
        float t1 = 0.f, t2 = 0.f;
        float y[16];
#pragma unroll
        for (int i = 0; i < 16; ++i) { y[i] = x[i] + p[i]; t1 += y[i]; t2 = fmaf(y[i], y[i], t2); }
        t1 = gsum16(t1); t2 = gsum16(t2);
        float muy = t1 * (1.0f / Dn);
        float vay = t2 * (1.0f / Dn) - muy * muy;
        float rsy = rsqrtf(vay + EPSf);
        float kh[16];
#pragma unroll
        for (int v = 0; v < 4; ++v) {
            float4 gg = *(const float4*)(g4 + doff + v * 4);
            float4 bb = *(const float4*)(b4 + doff + v * 4);
            kh[v*4+0] = (y[v*4+0]-muy)*rsy*gg.x + bb.x;
            kh[v*4+1] = (y[v*4+1]-muy)*rsy*gg.y + bb.y;
            kh[v*4+2] = (y[v*4+2]-muy)*rsy*gg.z + bb.z;
            kh[v*4+3] = (y[v*4+3]-muy)*rsy*gg.w + bb.w;
        }
        bf16x8 kv0, kv1;
#pragma unroll
        for (int j = 0; j < 8; ++j) {
            kv0[j] = valid ? (short)f2bf(kh[j])     : (short)0;
            kv1[j] = valid ? (short)f2bf(kh[8 + j]) : (short)0;
        }
        unsigned short* dst = khL + rowL * LDSW + doff;
        *(bf16x8*)(dst)     = kv0;
        *(bf16x8*)(dst + 8) = kv1;

        // q . key_hat -> LDS
        const float* qrow = q + (size_t)sb * Dn + doff;
        float pq = 0.f;
#pragma unroll
        for (int v = 0; v < 4; ++v) {
            float4 q4 = *(const float4*)(qrow + v * 4);
            pq = fmaf(kh[v*4+0], q4.x, pq); pq = fmaf(kh[v*4+1], q4.y, pq);
            pq = fmaf(kh[v*4+2], q4.z, pq); pq = fmaf(kh[v*4+3], q4.w, pq);
        }
        pq = gsum16(pq);
        if (l16 == 0) qkhL[rowL] = pq;
    }

    __syncthreads();

    // ---- phase 2: GEMM from LDS, 2 mtiles x 4 ntiles x 8 ktiles per wave ----
    f32x4 acc[2][4];
#pragma unroll
    for (int mt = 0; mt < 2; ++mt)
#pragma unroll
        for (int nt = 0; nt < 4; ++nt) { acc[mt][nt][0]=0.f; acc[mt][nt][1]=0.f; acc[mt][nt][2]=0.f; acc[mt][nt][3]=0.f; }

    int arow = lane & 15;
    int acol = (lane >> 4) * 8;
    const unsigned short* aL = khL + arow * LDSW + acol;
    const unsigned short* bbase = wfrag + (size_t)(wv * 4) * 64 * 8 + (size_t)lane * 8;

#pragma unroll
    for (int kt = 0; kt < 8; ++kt) {
        bf16x8 af0 = *(const bf16x8*)(aL + kt * 32);
        bf16x8 af1 = *(const bf16x8*)(aL + 16 * LDSW + kt * 32);
#pragma unroll
        for (int nt = 0; nt < 4; ++nt) {
            bf16x8 bf = *(const bf16x8*)(bbase + ((size_t)(kt * 16 + nt) * 64) * 8);
            acc[0][nt] = __builtin_amdgcn_mfma_f32_16x16x32_bf16(af0, bf, acc[0][nt], 0, 0, 0);
            acc[1][nt] = __builtin_amdgcn_mfma_f32_16x16x32_bf16(af1, bf, acc[1][nt], 0, 0, 0);
        }
    }

    // epilogue: partial[row] = sum_d q[d]*relu(T[row][d] + Wb[d]) over this wave's 64 d-cols
    int col = lane & 15, quad = lane >> 4;
    float qv[4], wbv[4];
#pragma unroll
    for (int nt = 0; nt < 4; ++nt) {
        int d = (wv * 4 + nt) * 16 + col;
        qv[nt] = q[(size_t)sb * Dn + d];
        wbv[nt] = Wb[d];
    }
#pragma unroll
    for (int mt = 0; mt < 2; ++mt) {
#pragma unroll
        for (int j = 0; j < 4; ++j) {
            float t = 0.f;
#pragma unroll
            for (int nt = 0; nt < 4; ++nt) {
                float v = acc[mt][nt][j] + wbv[nt];
                v = fmaxf(v, 0.f);
                t = fmaf(qv[nt], v, t);
            }
            t += __shfl_xor(t, 1, 64);
            t += __shfl_xor(t, 2, 64);
            t += __shfl_xor(t, 4, 64);
            t += __shfl_xor(t, 8, 64);
            if (col == 0) part[wv][mt * 16 + quad * 4 + j] = t;
        }
    }
    __syncthreads();
    int t = threadIdx.x;
    if (t < 32) {
        int l = mtg * 32 + t;
        if (l < Ln)
            wlogit[(size_t)sb * Ln + l] = qkhL[t]
                + part[0][t] + part[1][t] + part[2][t] + part[3][t];
    }
}

// ---------------- softmax over L per (s,b) ----------------
__global__ __launch_bounds__(256) void ksoft(const float* __restrict__ wlogit, float* __restrict__ wsoft)
{
    int sb = blockIdx.x, t = threadIdx.x;
    __shared__ float red[4];
    float lg = (t < Ln) ? wlogit[(size_t)sb * Ln + t] * SCALEf : -1e30f;
    float m = lg;
#pragma unroll
    for (int mk = 32; mk >= 1; mk >>= 1) m = fmaxf(m, __shfl_xor(m, mk, 64));
    if ((t & 63) == 0) red[t >> 6] = m;
    __syncthreads();
    m = fmaxf(fmaxf(red[0], red[1]), fmaxf(red[2], red[3]));
    __syncthreads();
    float ex = (t < Ln) ? __expf(lg - m) : 0.f;
    float sm = ex;
#pragma unroll
    for (int mk = 32; mk >= 1; mk >>= 1) sm += __shfl_xor(sm, mk, 64);
    if ((t & 63) == 0) red[t >> 6] = sm;
    __syncthreads();
    sm = red[0] + red[1] + red[2] + red[3];
    if (t < Ln) wsoft[(size_t)sb * Ln + t] = ex / sm;
}

// ---------------- output: sum of LN5(score*w*item) over both sources ----------------
// 4 (b,l) rows per block, 64 lanes per row, float4 per lane
__global__ __launch_bounds__(256) void kout(
    const float* __restrict__ loc, const float* __restrict__ glob,
    const float* __restrict__ score, const float* __restrict__ stats, const float* __restrict__ wsoft,
    const float* __restrict__ g5, const float* __restrict__ b5, float* __restrict__ out)
{
    int rr = threadIdx.x >> 6;
    int lane = threadIdx.x & 63;
    int row = blockIdx.x * 4 + rr;                   // (b,l) flat
    int b = row / Ln, l = row % Ln;
    size_t r0 = (size_t)b * Ln + l;
    size_t r1 = (size_t)(Bn + b) * Ln + l;

    float4 x0 = *(const float4*)(loc + (size_t)row * Dn + lane * 4);
    float4 x1 = *(const float4*)(glob + (size_t)row * Dn + lane * 4);
    float2 st0 = *(const float2*)(stats + 2 * r0);
    float2 st1 = *(const float2*)(stats + 2 * r1);
    float w0 = wsoft[r0], w1 = wsoft[r1];
    float4 g5v = *(const float4*)(g5 + lane * 4);
    float4 b5v = *(const float4*)(b5 + lane * 4);

    float4 dx0, dx1;
    dx0.x = x0.x - st0.x; dx0.y = x0.y - st0.x; dx0.z = x0.z - st0.x; dx0.w = x0.w - st0.x;
    dx1.x = x1.x - st1.x; dx1.y = x1.y - st1.x; dx1.z = x1.z - st1.x; dx1.w = x1.w - st1.x;

    float* obase = out + ((size_t)b * Kn * Ln + l) * Dn + lane * 4;
#pragma unroll
    for (int k = 0; k < Kn; ++k) {
        float c0 = score[r0 * Kn + k] * w0;
        float c1 = score[r1 * Kn + k] * w1;
        float a0 = c0 * rsqrtf(fmaf(c0 * c0, st0.y, EPSf));
        float a1 = c1 * rsqrtf(fmaf(c1 * c1, st1.y, EPSf));
        float4 o;
        o.x = fmaf(g5v.x, fmaf(a0, dx0.x, a1 * dx1.x), 2.0f * b5v.x);
        o.y = fmaf(g5v.y, fmaf(a0, dx0.y, a1 * dx1.y), 2.0f * b5v.y);
        o.z = fmaf(g5v.z, fmaf(a0, dx0.z, a1 * dx1.z), 2.0f * b5v.z);
        o.w = fmaf(g5v.w, fmaf(a0, dx0.w, a1 * dx1.w), 2.0f * b5v.w);
        *(float4*)(obase + (size_t)k * Ln * Dn) = o;
    }
}

extern "C" void kernel_launch(void* const* d_in, const int* in_sizes, int n_in,
                              void* d_out, int out_size, void* d_ws, size_t ws_size,
                              hipStream_t stream) {
    const float* loc   = (const float*)d_in[0];
    const float* glob  = (const float*)d_in[1];
    const float* inten = (const float*)d_in[2];
    const float* pos   = (const float*)d_in[3];
    const float* rou   = (const float*)d_in[4];
    const float* Ww    = (const float*)d_in[5];
    const float* Wb    = (const float*)d_in[6];
    const float* g1 = (const float*)d_in[7],  *b1 = (const float*)d_in[8];
    const float* g2 = (const float*)d_in[9],  *b2 = (const float*)d_in[10];
    const float* g3 = (const float*)d_in[11], *b3 = (const float*)d_in[12];
    const float* g4 = (const float*)d_in[13], *b4 = (const float*)d_in[14];
    const float* g5 = (const float*)d_in[15], *b5 = (const float*)d_in[16];
    const int* seq_len = (const int*)d_in[17];
    float* out = (float*)d_out;

    char* ws = (char*)d_ws;
    size_t off = 0;
    float* i2hat = (float*)(ws + off);            off += (size_t)Kn * Dn * 4;
    float* q     = (float*)(ws + off);            off += (size_t)2 * Bn * Dn * 4;
    unsigned short* wfrag = (unsigned short*)(ws + off); off += (size_t)Dn * Dn * 2;
    float* score  = (float*)(ws + off);           off += (size_t)2 * Bn * Ln * Kn * 4;
    float* stats  = (float*)(ws + off);           off += (size_t)2 * Bn * Ln * 2 * 4;
    float* wlogit = (float*)(ws + off);           off += (size_t)2 * Bn * Ln * 4;
    float* wsoft  = (float*)(ws + off);           off += (size_t)2 * Bn * Ln * 4;

    kprep<<<66, 256, 0, stream>>>(inten, g2, b2, loc, glob, pos, rou, g3, b3, seq_len, Ww,
                                  i2hat, q, wfrag);
    kfused<<<128 * 7, 256, 0, stream>>>(loc, glob, pos, g1, b1, g4, b4, i2hat, q,
                                        wfrag, Wb, score, stats, wlogit);
    ksoft<<<2 * Bn, 256, 0, stream>>>(wlogit, wsoft);
    kout<<<Bn * Ln / 4, 256, 0, stream>>>(loc, glob, score, stats, wsoft, g5, b5, out);
}